// Round 5
// baseline (373.741 us; speedup 1.0000x reference)
//
#include <hip/hip_runtime.h>
#include <stdint.h>

#define B_   32
#define CIN  256
#define COUT 512
#define HW_  4096
#define NT   32          // n per tile
#define TPB  8           // tiles per block

typedef short  short8  __attribute__((ext_vector_type(8)));
typedef float  float4_ __attribute__((ext_vector_type(4)));

__device__ __forceinline__ unsigned f2bf(float f) {
    unsigned u = __float_as_uint(f);
    u += 0x7FFFu + ((u >> 16) & 1u);   // RNE to bf16
    return u >> 16;
}
__device__ __forceinline__ float bf2f(unsigned h) {
    return __uint_as_float(h << 16);
}

// Kernel 0 (grid 64):
//  blocks 0..31  : zero P/T, ggbx[b][a] = g@Wg.T + bg + bx
//  blocks 32..63 : WxR fragment-linear repack of Wx (bf16)
//    entry e = ((w*8+kk)*4+ai)*64 + lane  holds Wx[a=w*64+ai*16+(lane&15)]
//                                              [k=kk*32+(lane>>4)*8 .. +7]
__global__ __launch_bounds__(256) void prep_kernel(
    const float* __restrict__ g, const float* __restrict__ Wg,
    const float* __restrict__ bg, const float* __restrict__ Wx,
    const float* __restrict__ bx,
    uint4* __restrict__ WxR, float* __restrict__ ggbx,
    float* __restrict__ P, float* __restrict__ T)
{
    int t = threadIdx.x;
    if (blockIdx.x >= 32) {
        int e = (blockIdx.x - 32) * 256 + t;
        int lane = e & 63, ai = (e >> 6) & 3, kk = (e >> 8) & 7, w = e >> 11;
        int a  = w * 64 + ai * 16 + (lane & 15);
        int kb = kk * 32 + (lane >> 4) * 8;
        const float4* s = (const float4*)(Wx + (size_t)a * 256 + kb);
        float4 u0 = s[0], u1 = s[1];
        uint4 pk;
        pk.x = f2bf(u0.x) | (f2bf(u0.y) << 16);
        pk.y = f2bf(u0.z) | (f2bf(u0.w) << 16);
        pk.z = f2bf(u1.x) | (f2bf(u1.y) << 16);
        pk.w = f2bf(u1.z) | (f2bf(u1.w) << 16);
        WxR[e] = pk;
        return;
    }
    int b = blockIdx.x;
    int i = b * 256 + t;
    P[i] = 0.f; T[i] = 0.f;

    __shared__ float gl[COUT];
    gl[t]       = g[b * COUT + t];
    gl[t + 256] = g[b * COUT + 256 + t];
    __syncthreads();

    float acc0 = bg[t] + bx[t], acc1 = 0.f;    // a = t, dual chain for ILP
    const float4* wr = (const float4*)(Wg + (size_t)t * COUT);
    #pragma unroll 8
    for (int co = 0; co < COUT / 4; co += 2) {
        float4 wv0 = wr[co],     gv0 = *(const float4*)&gl[co * 4];
        float4 wv1 = wr[co + 1], gv1 = *(const float4*)&gl[co * 4 + 4];
        acc0 += wv0.x * gv0.x + wv0.y * gv0.y + wv0.z * gv0.z + wv0.w * gv0.w;
        acc1 += wv1.x * gv1.x + wv1.y * gv1.y + wv1.z * gv1.z + wv1.w * gv1.w;
    }
    ggbx[b * 256 + t] = acc0 + acc1;
}

// Kernel 1: grid 512, each block owns 8 consecutive n-tiles of 32 within one b.
// Cross-tile pipeline: prefetch tile i+1's fp32 x into registers while
// computing tile i (GEMM + epilogue + pooling from bf16 LDS).
// LDS word swizzle: chunk position p = (ch ^ n ^ (n>>3)) & 31.
__global__ __launch_bounds__(256, 3) void attn_main(
    const float* __restrict__ x, const char* __restrict__ WxR,
    const float* __restrict__ ggbx, const float* __restrict__ Wf,
    const float* __restrict__ bfs,
    float* __restrict__ P, float* __restrict__ T, float* __restrict__ raw)
{
    __shared__ unsigned int xT[NT * 128];      // 16 KB: [n][32 chunks][4 words]
    __shared__ float att_part[4][NT];
    __shared__ float raw_l[NT];

    int bl = blockIdx.x;
    int b   = bl >> 4;                         // 16 blocks per batch
    int nt0 = (bl & 15) * TPB;                 // tile index base
    int t = threadIdx.x, w = t >> 6, lane = t & 63;
    int quad = lane >> 4, l15 = lane & 15;

    const float* xb = x + (size_t)b * CIN * HW_;

    // staging geometry: thread owns 8 consecutive c-rows at 4 consecutive n
    int sub = lane >> 3, n4 = (lane & 7) * 4;
    int cbase = w * 64 + sub * 8;
    int ch = cbase >> 3;                       // this thread's chunk id

    // per-wave a-range: a = w*64 + ai*16 + l15 (b fixed for whole block)
    float ga[4], wfv[4];
    #pragma unroll
    for (int ai = 0; ai < 4; ai++) {
        int a = w * 64 + ai * 16 + l15;
        ga[ai]  = ggbx[b * 256 + a];
        wfv[ai] = Wf[a];
    }
    float bfv = bfs[0];

    const char* wsl = WxR + w * 32768 + lane * 16;   // wave's B-fragment slice

    float pp_tot = 0.f, tt_tot = 0.f;          // pooling partials for c = t

    float4_ v[8];                              // prefetch registers (32 VGPR)
    auto LOADX = [&](int nt) {
        const float* p0 = xb + (size_t)cbase * HW_ + nt * NT + n4;
        #pragma unroll
        for (int j = 0; j < 8; j++)
            v[j] = *(const float4_*)(p0 + (size_t)j * HW_);
    };
    auto STAGE = [&]() {                       // pack v -> bf16 LDS tile
        #pragma unroll
        for (int r = 0; r < 4; r++) {
            uint4 pk;
            pk.x = f2bf(v[0][r]) | (f2bf(v[1][r]) << 16);
            pk.y = f2bf(v[2][r]) | (f2bf(v[3][r]) << 16);
            pk.z = f2bf(v[4][r]) | (f2bf(v[5][r]) << 16);
            pk.w = f2bf(v[6][r]) | (f2bf(v[7][r]) << 16);
            int n = n4 + r;
            int p = (ch ^ n ^ (n >> 3)) & 31;
            *(uint4*)&xT[n * 128 + p * 4] = pk;
        }
    };

    LOADX(nt0);
    STAGE();
    __syncthreads();

    for (int i = 0; i < TPB; i++) {
        int nt = nt0 + i;
        if (i < TPB - 1) LOADX(nt + 1);        // prefetch overlaps everything below

        // ---- GEMM: D[m=n][col=a] = x^T * Wx^T ----
        float4_ acc[2][4];
        #pragma unroll
        for (int mi = 0; mi < 2; mi++)
            #pragma unroll
            for (int ai = 0; ai < 4; ai++)
                acc[mi][ai] = (float4_){0.f, 0.f, 0.f, 0.f};

        short8 af[2], bfA[4], bfB[4];
        auto LDA = [&](int k0) {
            int qk = (k0 >> 3) + quad;
            #pragma unroll
            for (int mi = 0; mi < 2; mi++) {
                int n = mi * 16 + l15;
                int p = (qk ^ n ^ (n >> 3)) & 31;
                af[mi] = *(const short8*)&xT[n * 128 + p * 4];
            }
        };
        auto LDB = [&](short8* bf, int k0) {
            const char* wk = wsl + (k0 >> 5) * 4096;
            #pragma unroll
            for (int ai = 0; ai < 4; ai++)
                bf[ai] = *(const short8*)(wk + ai * 1024);
        };
        auto MM = [&](short8* bf) {
            #pragma unroll
            for (int mi = 0; mi < 2; mi++)
                #pragma unroll
                for (int ai = 0; ai < 4; ai++)
                    acc[mi][ai] = __builtin_amdgcn_mfma_f32_16x16x32_bf16(
                        af[mi], bf[ai], acc[mi][ai], 0, 0, 0);
        };

        LDB(bfA, 0);
        LDB(bfB, 32);
        #pragma unroll
        for (int k0 = 0; k0 < 256; k0 += 64) {
            LDA(k0);      MM(bfA);  if (k0 < 192) LDB(bfA, k0 + 64);
            LDA(k0 + 32); MM(bfB);  if (k0 < 192) LDB(bfB, k0 + 96);
        }

        // ---- epilogue: relu(D + gg) * Wf, reduce over a ----
        #pragma unroll
        for (int mi = 0; mi < 2; mi++) {
            float p[4] = {0.f, 0.f, 0.f, 0.f};
            #pragma unroll
            for (int ai = 0; ai < 4; ai++) {
                #pragma unroll
                for (int r = 0; r < 4; r++) {
                    float vv = acc[mi][ai][r] + ga[ai];
                    vv = fmaxf(vv, 0.f);
                    p[r] = fmaf(vv, wfv[ai], p[r]);
                }
            }
            #pragma unroll
            for (int r = 0; r < 4; r++) {
                #pragma unroll
                for (int off = 1; off < 16; off <<= 1)
                    p[r] += __shfl_xor(p[r], off, 16);
            }
            if (l15 == 0) {
                #pragma unroll
                for (int r = 0; r < 4; r++)
                    att_part[w][mi * 16 + quad * 4 + r] = p[r];
            }
        }
        __syncthreads();

        if (t < NT) {
            float rv = att_part[0][t] + att_part[1][t] + att_part[2][t]
                     + att_part[3][t] + bfv;
            raw[b * HW_ + nt * NT + t] = rv;
            raw_l[t] = rv;
        }
        __syncthreads();

        // ---- pooling partials from bf16 LDS: thread owns c = t ----
        {
            int chp = t >> 3, qw = (t >> 1) & 3, hi = t & 1;
            #pragma unroll
            for (int n = 0; n < NT; n++) {
                int p = (chp ^ n ^ (n >> 3)) & 31;
                unsigned u = xT[n * 128 + p * 4 + qw];
                float xv = bf2f(hi ? (u >> 16) : (u & 0xFFFFu));
                pp_tot = fmaf(xv, raw_l[n], pp_tot);
                tt_tot += xv;
            }
        }
        __syncthreads();                       // WAR on xT before restaging

        if (i < TPB - 1) {
            STAGE();                           // consumes prefetch (vmcnt waits here)
            __syncthreads();
        }
    }

    atomicAdd(&P[b * 256 + t], pp_tot);
    atomicAdd(&T[b * 256 + t], tt_tot);
}

// Kernel 2: per batch: min/sum over raw, write att output and pooled out
__global__ __launch_bounds__(256) void finalize_kernel(
    const float* __restrict__ raw, const float* __restrict__ P,
    const float* __restrict__ T, float* __restrict__ out)
{
    int b = blockIdx.x, t = threadIdx.x;
    const float* r = raw + (size_t)b * HW_;
    float v[16];
    float mn = 3.4e38f, sm = 0.f;
    #pragma unroll
    for (int i = 0; i < 16; i++) {
        v[i] = r[t + 256 * i];
        mn = fminf(mn, v[i]);
        sm += v[i];
    }
    #pragma unroll
    for (int off = 1; off < 64; off <<= 1) {
        mn = fminf(mn, __shfl_xor(mn, off, 64));
        sm += __shfl_xor(sm, off, 64);
    }
    __shared__ float smn[4], ssm[4];
    int w = t >> 6;
    if ((t & 63) == 0) { smn[w] = mn; ssm[w] = sm; }
    __syncthreads();
    mn = fminf(fminf(smn[0], smn[1]), fminf(smn[2], smn[3]));
    sm = (ssm[0] + ssm[1]) + (ssm[2] + ssm[3]);
    float S = sm - 4096.f * mn;                 // sum of (raw - min)
    float inv = 1.f / S;

    float* att = out + B_ * CIN + (size_t)b * HW_;
    #pragma unroll
    for (int i = 0; i < 16; i++) att[t + 256 * i] = (v[i] - mn) * inv;

    int ic = b * 256 + t;
    out[ic] = (P[ic] - mn * T[ic]) * inv;
}

extern "C" void kernel_launch(void* const* d_in, const int* in_sizes, int n_in,
                              void* d_out, int out_size, void* d_ws, size_t ws_size,
                              hipStream_t stream)
{
    const float* x   = (const float*)d_in[0];
    const float* g   = (const float*)d_in[1];
    const float* Wg  = (const float*)d_in[2];
    const float* bg  = (const float*)d_in[3];
    const float* Wx  = (const float*)d_in[4];
    const float* bx  = (const float*)d_in[5];
    const float* Wf  = (const float*)d_in[6];
    const float* bf  = (const float*)d_in[7];
    float* out = (float*)d_out;

    char* wsb = (char*)d_ws;
    uint4* WxR  = (uint4*)wsb;                            // 128 KB
    float* ggbx = (float*)(wsb + 131072);                 // 32 KB
    float* P    = ggbx + 8192;                            // 32 KB
    float* T    = P + 8192;                               // 32 KB
    float* raw  = T + 8192;                               // 512 KB

    prep_kernel<<<64, 256, 0, stream>>>(g, Wg, bg, Wx, bx, WxR, ggbx, P, T);
    attn_main<<<512, 256, 0, stream>>>(x, (const char*)WxR, ggbx, Wf, bf, P, T, raw);
    finalize_kernel<<<32, 256, 0, stream>>>(raw, P, T, out);
}

// Round 6
// 243.860 us; speedup vs baseline: 1.5326x; 1.5326x over previous
//
#include <hip/hip_runtime.h>
#include <stdint.h>

#define B_   32
#define CIN  256
#define COUT 512
#define HW_  4096
#define NT   32          // n per tile
#define NTILE 128        // tiles per batch

typedef short  short8  __attribute__((ext_vector_type(8)));
typedef float  float4_ __attribute__((ext_vector_type(4)));

__device__ __forceinline__ unsigned f2bf(float f) {
    unsigned u = __float_as_uint(f);
    u += 0x7FFFu + ((u >> 16) & 1u);   // RNE to bf16
    return u >> 16;
}
__device__ __forceinline__ float bf2f(unsigned h) {
    return __uint_as_float(h << 16);
}

// Kernel 0 (grid 64):
//  blocks 0..31  : ggbx[b][a] = g@Wg.T + bg + bx
//  blocks 32..63 : WxR fragment-linear repack of Wx (bf16)
//    entry e = ((w*8+kk)*4+ai)*64 + lane  holds Wx[a=w*64+ai*16+(lane&15)]
//                                              [k=kk*32+(lane>>4)*8 .. +7]
__global__ __launch_bounds__(256) void prep_kernel(
    const float* __restrict__ g, const float* __restrict__ Wg,
    const float* __restrict__ bg, const float* __restrict__ Wx,
    const float* __restrict__ bx,
    uint4* __restrict__ WxR, float* __restrict__ ggbx)
{
    int t = threadIdx.x;
    if (blockIdx.x >= 32) {
        int e = (blockIdx.x - 32) * 256 + t;
        int lane = e & 63, ai = (e >> 6) & 3, kk = (e >> 8) & 7, w = e >> 11;
        int a  = w * 64 + ai * 16 + (lane & 15);
        int kb = kk * 32 + (lane >> 4) * 8;
        const float4* s = (const float4*)(Wx + (size_t)a * 256 + kb);
        float4 u0 = s[0], u1 = s[1];
        uint4 pk;
        pk.x = f2bf(u0.x) | (f2bf(u0.y) << 16);
        pk.y = f2bf(u0.z) | (f2bf(u0.w) << 16);
        pk.z = f2bf(u1.x) | (f2bf(u1.y) << 16);
        pk.w = f2bf(u1.z) | (f2bf(u1.w) << 16);
        WxR[e] = pk;
        return;
    }
    int b = blockIdx.x;

    __shared__ float gl[COUT];
    gl[t]       = g[b * COUT + t];
    gl[t + 256] = g[b * COUT + 256 + t];
    __syncthreads();

    float acc0 = bg[t] + bx[t], acc1 = 0.f;    // a = t, dual chain for ILP
    const float4* wr = (const float4*)(Wg + (size_t)t * COUT);
    #pragma unroll 8
    for (int co = 0; co < COUT / 4; co += 2) {
        float4 wv0 = wr[co],     gv0 = *(const float4*)&gl[co * 4];
        float4 wv1 = wr[co + 1], gv1 = *(const float4*)&gl[co * 4 + 4];
        acc0 += wv0.x * gv0.x + wv0.y * gv0.y + wv0.z * gv0.z + wv0.w * gv0.w;
        acc1 += wv1.x * gv1.x + wv1.y * gv1.y + wv1.z * gv1.z + wv1.w * gv1.w;
    }
    ggbx[b * 256 + t] = acc0 + acc1;
}

// Kernel 1: grid 4096, one (b, 32-n tile) per block.
// Stage x tile (fp32 global -> regs -> bf16 LDS, XOR-swizzled), MFMA GEMM
// against fragment-linear WxR, relu+Wf epilogue -> raw, pooling partials
// written non-atomically to Ppart/Tpart[b][tile][c].
__global__ __launch_bounds__(256, 4) void attn_main(
    const float* __restrict__ x, const char* __restrict__ WxR,
    const float* __restrict__ ggbx, const float* __restrict__ Wf,
    const float* __restrict__ bfs,
    float* __restrict__ Ppart, float* __restrict__ Tpart,
    float* __restrict__ raw)
{
    __shared__ unsigned int xT[NT * 128];      // 16 KB: [n][32 chunks][4 words]
    __shared__ float att_part[4][NT];
    __shared__ float raw_l[NT];

    int bid = blockIdx.x;
    int b  = bid >> 7;                         // 128 tiles per batch
    int nt = bid & 127;
    int t = threadIdx.x, w = t >> 6, lane = t & 63;
    int quad = lane >> 4, l15 = lane & 15;

    // staging geometry: thread owns 8 consecutive c-rows at 4 consecutive n
    int sub = lane >> 3, n4 = (lane & 7) * 4;
    int cbase = w * 64 + sub * 8;
    int ch = cbase >> 3;                       // this thread's chunk id

    // ---- load 8 float4 (dies before K-loop; no long-lived registers) ----
    {
        const float* p0 = x + (size_t)b * CIN * HW_ + (size_t)cbase * HW_
                        + nt * NT + n4;
        float4_ v[8];
        #pragma unroll
        for (int j = 0; j < 8; j++)
            v[j] = *(const float4_*)(p0 + (size_t)j * HW_);
        #pragma unroll
        for (int r = 0; r < 4; r++) {
            uint4 pk;
            pk.x = f2bf(v[0][r]) | (f2bf(v[1][r]) << 16);
            pk.y = f2bf(v[2][r]) | (f2bf(v[3][r]) << 16);
            pk.z = f2bf(v[4][r]) | (f2bf(v[5][r]) << 16);
            pk.w = f2bf(v[6][r]) | (f2bf(v[7][r]) << 16);
            int n = n4 + r;
            int p = (ch ^ n ^ (n >> 3)) & 31;
            *(uint4*)&xT[n * 128 + p * 4] = pk;
        }
    }

    // per-wave a-range: a = w*64 + ai*16 + l15 (overlaps staging latency)
    float ga[4], wfv[4];
    #pragma unroll
    for (int ai = 0; ai < 4; ai++) {
        int a = w * 64 + ai * 16 + l15;
        ga[ai]  = ggbx[b * 256 + a];
        wfv[ai] = Wf[a];
    }
    float bfv = bfs[0];
    __syncthreads();

    // ---- GEMM: D[m=n][col=a] = x^T * Wx^T, pipelined WxR loads ----
    const char* wsl = WxR + w * 32768 + lane * 16;   // wave's B-fragment slice
    float4_ acc[2][4];
    #pragma unroll
    for (int mi = 0; mi < 2; mi++)
        #pragma unroll
        for (int ai = 0; ai < 4; ai++)
            acc[mi][ai] = (float4_){0.f, 0.f, 0.f, 0.f};

    short8 af[2], bfA[4], bfB[4];
    auto LDA = [&](int k0) {
        int qk = (k0 >> 3) + quad;
        #pragma unroll
        for (int mi = 0; mi < 2; mi++) {
            int n = mi * 16 + l15;
            int p = (qk ^ n ^ (n >> 3)) & 31;
            af[mi] = *(const short8*)&xT[n * 128 + p * 4];
        }
    };
    auto LDB = [&](short8* bf, int k0) {
        const char* wk = wsl + (k0 >> 5) * 4096;
        #pragma unroll
        for (int ai = 0; ai < 4; ai++)
            bf[ai] = *(const short8*)(wk + ai * 1024);
    };
    auto MM = [&](short8* bf) {
        #pragma unroll
        for (int mi = 0; mi < 2; mi++)
            #pragma unroll
            for (int ai = 0; ai < 4; ai++)
                acc[mi][ai] = __builtin_amdgcn_mfma_f32_16x16x32_bf16(
                    af[mi], bf[ai], acc[mi][ai], 0, 0, 0);
    };

    LDB(bfA, 0);
    LDB(bfB, 32);
    #pragma unroll
    for (int k0 = 0; k0 < 256; k0 += 64) {
        LDA(k0);      MM(bfA);  if (k0 < 192) LDB(bfA, k0 + 64);
        LDA(k0 + 32); MM(bfB);  if (k0 < 192) LDB(bfB, k0 + 96);
    }

    // ---- epilogue: relu(D + gg) * Wf, reduce over a ----
    #pragma unroll
    for (int mi = 0; mi < 2; mi++) {
        float p[4] = {0.f, 0.f, 0.f, 0.f};
        #pragma unroll
        for (int ai = 0; ai < 4; ai++) {
            #pragma unroll
            for (int r = 0; r < 4; r++) {
                float vv = acc[mi][ai][r] + ga[ai];
                vv = fmaxf(vv, 0.f);
                p[r] = fmaf(vv, wfv[ai], p[r]);
            }
        }
        #pragma unroll
        for (int r = 0; r < 4; r++) {
            #pragma unroll
            for (int off = 1; off < 16; off <<= 1)
                p[r] += __shfl_xor(p[r], off, 16);
        }
        if (l15 == 0) {
            #pragma unroll
            for (int r = 0; r < 4; r++)
                att_part[w][mi * 16 + quad * 4 + r] = p[r];
        }
    }
    __syncthreads();

    if (t < NT) {
        float rv = att_part[0][t] + att_part[1][t] + att_part[2][t]
                 + att_part[3][t] + bfv;
        raw[b * HW_ + nt * NT + t] = rv;
        raw_l[t] = rv;
    }
    __syncthreads();

    // ---- pooling partials from bf16 LDS: thread owns c = t ----
    float pp = 0.f, tt = 0.f;
    {
        int chp = t >> 3, qw = (t >> 1) & 3, hi = t & 1;
        #pragma unroll
        for (int n = 0; n < NT; n++) {
            int p = (chp ^ n ^ (n >> 3)) & 31;
            unsigned u = xT[n * 128 + p * 4 + qw];
            float xv = bf2f(hi ? (u >> 16) : (u & 0xFFFFu));
            pp = fmaf(xv, raw_l[n], pp);
            tt += xv;
        }
    }
    // non-atomic partial dump: coalesced 1 KB per wave
    size_t pbase = ((size_t)b * NTILE + nt) * 256 + t;
    Ppart[pbase] = pp;
    Tpart[pbase] = tt;
}

// Kernel 2: per batch: min/sum over raw, write att output; sum Ppart/Tpart
// over tiles and write pooled out.
__global__ __launch_bounds__(256) void finalize_kernel(
    const float* __restrict__ raw, const float* __restrict__ Ppart,
    const float* __restrict__ Tpart, float* __restrict__ out)
{
    int b = blockIdx.x, t = threadIdx.x;
    const float* r = raw + (size_t)b * HW_;
    float v[16];
    float mn = 3.4e38f, sm = 0.f;
    #pragma unroll
    for (int i = 0; i < 16; i++) {
        v[i] = r[t + 256 * i];
        mn = fminf(mn, v[i]);
        sm += v[i];
    }
    #pragma unroll
    for (int off = 1; off < 64; off <<= 1) {
        mn = fminf(mn, __shfl_xor(mn, off, 64));
        sm += __shfl_xor(sm, off, 64);
    }
    __shared__ float smn[4], ssm[4];
    int w = t >> 6;
    if ((t & 63) == 0) { smn[w] = mn; ssm[w] = sm; }
    __syncthreads();
    mn = fminf(fminf(smn[0], smn[1]), fminf(smn[2], smn[3]));
    sm = (ssm[0] + ssm[1]) + (ssm[2] + ssm[3]);
    float S = sm - 4096.f * mn;                 // sum of (raw - min)
    float inv = 1.f / S;

    float* att = out + B_ * CIN + (size_t)b * HW_;
    #pragma unroll
    for (int i = 0; i < 16; i++) att[t + 256 * i] = (v[i] - mn) * inv;

    // sum pooling partials over 128 tiles (4 independent chains for MLP)
    const float* pb = Ppart + (size_t)b * NTILE * 256 + t;
    const float* tb = Tpart + (size_t)b * NTILE * 256 + t;
    float P0 = 0.f, P1 = 0.f, T0 = 0.f, T1 = 0.f;
    #pragma unroll 8
    for (int tau = 0; tau < NTILE; tau += 2) {
        P0 += pb[tau * 256];
        P1 += pb[(tau + 1) * 256];
        T0 += tb[tau * 256];
        T1 += tb[(tau + 1) * 256];
    }
    out[b * 256 + t] = ((P0 + P1) - mn * (T0 + T1)) * inv;
}

extern "C" void kernel_launch(void* const* d_in, const int* in_sizes, int n_in,
                              void* d_out, int out_size, void* d_ws, size_t ws_size,
                              hipStream_t stream)
{
    const float* x   = (const float*)d_in[0];
    const float* g   = (const float*)d_in[1];
    const float* Wg  = (const float*)d_in[2];
    const float* bg  = (const float*)d_in[3];
    const float* Wx  = (const float*)d_in[4];
    const float* bx  = (const float*)d_in[5];
    const float* Wf  = (const float*)d_in[6];
    const float* bf  = (const float*)d_in[7];
    float* out = (float*)d_out;

    char* wsb = (char*)d_ws;
    uint4* WxR   = (uint4*)wsb;                           // 128 KB
    float* ggbx  = (float*)(wsb + (128 << 10));           // 32 KB
    float* raw   = (float*)(wsb + (160 << 10));           // 512 KB
    float* Ppart = (float*)(wsb + (672 << 10));           // 4 MB
    float* Tpart = Ppart + (size_t)B_ * NTILE * 256;      // 4 MB

    prep_kernel<<<64, 256, 0, stream>>>(g, Wg, bg, Wx, bx, WxR, ggbx);
    attn_main<<<4096, 256, 0, stream>>>(x, (const char*)WxR, ggbx, Wf, bf,
                                        Ppart, Tpart, raw);
    finalize_kernel<<<32, 256, 0, stream>>>(raw, Ppart, Tpart, out);
}